// Round 1
// baseline (496.937 us; speedup 1.0000x reference)
//
#include <hip/hip_runtime.h>
#include <hip/hip_bf16.h>

#define B_ 16
#define C_ 512
#define N_ 4096
#define EPSV 1e-6f

typedef __attribute__((ext_vector_type(8))) short bffrag;     // 8 bf16 (4 VGPR) MFMA A/B frag
typedef __attribute__((ext_vector_type(4))) float f32x4;      // MFMA C/D frag
typedef __attribute__((ext_vector_type(2))) unsigned short us2;
typedef __attribute__((ext_vector_type(4))) unsigned short us4;
typedef __attribute__((ext_vector_type(8))) unsigned short us8;

__device__ __forceinline__ unsigned short f2bf(float f){
  unsigned u = __float_as_uint(f);
  u += 0x7fffu + ((u >> 16) & 1u);   // RNE; inputs are finite gaussians
  return (unsigned short)(u >> 16);
}

// async global->LDS, 16B/lane; LDS base must be wave-uniform, HW scatters
// lane i to base + i*16. Global source IS per-lane -> swizzled LDS layouts
// are done by pre-swizzling the global source address (m173 pattern).
__device__ __forceinline__ void gload_lds16(const void* g, void* l){
  __builtin_amdgcn_global_load_lds(
      (__attribute__((address_space(1))) void*)g,
      (__attribute__((address_space(3))) void*)l, 16, 0, 0);
}

// ---------------------------------------------------------------------------
// K1: fused reduce+prep. Block = (b, 64-n strip). Pass A: s, s2 per n.
// Pass B (L2-hot re-read): Ph[c][n]=bf16(V*sqrt(rnorm)) + LDS-transposed
// Pt[n][c] + tpart partials. Transpose phase now vectorized: us8 stores
// (16B) instead of scalar u16 stores (8x fewer store instructions).
// ---------------------------------------------------------------------------
__global__ __launch_bounds__(256) void k_prep(const float* __restrict__ x,
    unsigned short* __restrict__ Ph, unsigned short* __restrict__ Pt,
    float* __restrict__ vsum, float* __restrict__ sqg,
    float* __restrict__ tpart){
  __shared__ float sdA[16][64], sdB[16][64];
  __shared__ float sql[64], rql[64];
  __shared__ unsigned short qtl[512 * 66];   // [c][nloc], stride 66 breaks banks

  const int t = threadIdx.x;
  const int b = blockIdx.x >> 6, strip = blockIdx.x & 63, n0 = strip * 64;
  const int rg = t >> 4, n4 = t & 15;
  const float* xs = x + (size_t)b * C_ * N_ + n0;

  // pass A: column sums
  float4 s4 = {0,0,0,0}, s24 = {0,0,0,0};
  #pragma unroll 8
  for (int k = 0; k < 32; ++k){
    float4 v = *(const float4*)&xs[(size_t)(k * 16 + rg) * N_ + n4 * 4];
    s4.x += v.x; s4.y += v.y; s4.z += v.z; s4.w += v.w;
    s24.x += v.x * v.x; s24.y += v.y * v.y;
    s24.z += v.z * v.z; s24.w += v.w * v.w;
  }
  *(float4*)&sdA[rg][n4 * 4] = s4;
  *(float4*)&sdB[rg][n4 * 4] = s24;
  __syncthreads();
  if (t < 64){
    float s = 0.f, s2 = 0.f;
    #pragma unroll
    for (int g2 = 0; g2 < 16; ++g2){ s += sdA[g2][t]; s2 += sdB[g2][t]; }
    float rn = 1.0f / sqrtf(s2);
    float sq = sqrtf(rn);
    vsum[b * N_ + n0 + t] = s;
    sqg [b * N_ + n0 + t] = sq;
    sql[t] = sq;
    rql[t] = rn * (s * rn + EPSV);
  }
  __syncthreads();

  // pass B
  float4 sq4 = *(float4*)&sql[n4 * 4];
  float4 rq4 = *(float4*)&rql[n4 * 4];
  unsigned short* Php = Ph + (size_t)b * C_ * N_ + n0;
  float* tpp = tpart + ((size_t)b * 64 + strip) * C_;
  #pragma unroll 4
  for (int k = 0; k < 32; ++k){
    int c = k * 16 + rg;
    float4 v = *(const float4*)&xs[(size_t)c * N_ + n4 * 4];
    us2 p0, p1;
    p0.x = f2bf(v.x * sq4.x); p0.y = f2bf(v.y * sq4.y);
    p1.x = f2bf(v.z * sq4.z); p1.y = f2bf(v.w * sq4.w);
    us4 ph; ph.x = p0.x; ph.y = p0.y; ph.z = p1.x; ph.w = p1.y;
    *(us4*)&Php[(size_t)c * N_ + n4 * 4] = ph;
    *(us2*)&qtl[c * 66 + n4 * 4]     = p0;   // 4B-aligned (66c+4n4 even)
    *(us2*)&qtl[c * 66 + n4 * 4 + 2] = p1;
    float tp = v.x * rq4.x + v.y * rq4.y + v.z * rq4.z + v.w * rq4.w;
    tp += __shfl_down(tp, 8, 16);
    tp += __shfl_down(tp, 4, 16);
    tp += __shfl_down(tp, 2, 16);
    tp += __shfl_down(tp, 1, 16);
    if (n4 == 0) tpp[c] = tp;
  }
  __syncthreads();

  // transposed output Pt[b][n][c]: thread owns n-pair (t&31)*2, c-range
  // (t>>5)*64..+63. us2 LDS reads (conflict-free: bank = c*33 + n2>>1) feed
  // two us8 (16B) stores per 8-c group. L2 write-combines the 16B/1KB-stride
  // lane pattern (full 64KB strip is covered).
  {
    const int n2 = (t & 31) * 2, cg = (t >> 5) * 64;
    unsigned short* P0 = Pt + ((size_t)b * N_ + n0 + n2) * C_;
    unsigned short* P1 = P0 + C_;
    for (int k8 = 0; k8 < 8; ++k8){
      int c = cg + k8 * 8;
      us8 w0, w1;
      #pragma unroll
      for (int e = 0; e < 8; ++e){
        us2 v = *(const us2*)&qtl[(c + e) * 66 + n2];
        w0[e] = v.x; w1[e] = v.y;
      }
      *(us8*)&P0[c] = w0;
      *(us8*)&P1[c] = w1;
    }
  }
}

// ---------------------------------------------------------------------------
// K2: GEMM1  matrix = Ph @ Ph^T per batch, K=4096, bf16 out.
// 256 threads = 4 waves of 64x64 (4x4 frags: 4x/4x LDS reuse). BK=64,
// double-buffered LDS (64KB), prefetch issued before compute, one
// vmcnt-drain barrier per iter. LDS rows are 128B -> XOR-swizzle chunk^=row&7
// applied on the *global source* (gload_lds dest stays linear) and on reads.
// XCD-quad block swizzle: 2x2 tile quads (sharing 2 A + 2 B panels = 4MB)
// land on one XCD's L2. 256 main blocks (1/CU) + 16 tail blocks for tvec.
// ---------------------------------------------------------------------------
__global__ __launch_bounds__(256) void k_gemm1(const unsigned short* __restrict__ Ph,
    unsigned short* __restrict__ Ab, const float* __restrict__ tpart,
    float* __restrict__ tvec){
  const int bid = blockIdx.x;
  if (bid >= 256){                       // tail: tvec[b*C+c] = sum_strips tpart
    const int base = (bid - 256) * 512;
    for (int u = threadIdx.x; u < 512; u += 256){
      int i = base + u;
      const float* tp = tpart + (size_t)(i >> 9) * 64 * C_ + (i & 511);
      float s = 0.f;
      #pragma unroll 8
      for (int k = 0; k < 64; ++k) s += tp[(size_t)k * C_];
      tvec[i] = s;
    }
    return;
  }
  // bijective bid -> (b, c0, m0): XCD xcd = bid&7 owns quads xcd*8..xcd*8+7
  const int xcd = bid & 7, sq_ = bid >> 3;
  const int qg = xcd * 8 + (sq_ >> 2), sub = sq_ & 3;
  const int b = qg >> 2, qd = qg & 3;
  const int c0 = ((qd >> 1) * 2 + (sub >> 1)) * 128;
  const int m0 = ((qd & 1) * 2 + (sub & 1)) * 128;

  __shared__ unsigned short As[2][8192], Bs[2][8192];   // [buf][128 rows][64 k]

  const int t = threadIdx.x, lane = t & 63, wave = t >> 6;
  const int wr = (wave & 1) * 64, wc = (wave >> 1) * 64;
  const int fr = lane & 15, quad = lane >> 4;
  const int rxor = (fr & 7) << 4;        // read-side swizzle (row&7 == fr&7)

  // staging: call q covers rows q*32 + (t>>3); source chunk = (t&7) ^ (row&7)
  // (row&7 == (t>>3)&7 since q*32 = 0 mod 8 -> csel constant per thread)
  const int rq = t >> 3;
  const int csel = ((t & 7) ^ (rq & 7)) * 8;
  const unsigned short* Aga = Ph + (size_t)(b * C_ + c0 + rq) * N_ + csel;
  const unsigned short* Bga = Ph + (size_t)(b * C_ + m0 + rq) * N_ + csel;
  const int lo = wave * 512;             // elements; HW adds lane*8

  f32x4 acc[4][4];
  #pragma unroll
  for (int i = 0; i < 4; ++i)
    #pragma unroll
    for (int j = 0; j < 4; ++j) acc[i][j] = (f32x4){0.f, 0.f, 0.f, 0.f};

  auto stage = [&](int bufi, int k0){
    gload_lds16(Aga + k0,           &As[bufi][lo]);
    gload_lds16(Aga + 32 * N_ + k0, &As[bufi][2048 + lo]);
    gload_lds16(Aga + 64 * N_ + k0, &As[bufi][4096 + lo]);
    gload_lds16(Aga + 96 * N_ + k0, &As[bufi][6144 + lo]);
    gload_lds16(Bga + k0,           &Bs[bufi][lo]);
    gload_lds16(Bga + 32 * N_ + k0, &Bs[bufi][2048 + lo]);
    gload_lds16(Bga + 64 * N_ + k0, &Bs[bufi][4096 + lo]);
    gload_lds16(Bga + 96 * N_ + k0, &Bs[bufi][6144 + lo]);
  };

  stage(0, 0);
  __syncthreads();
  int cur = 0;
  for (int kc = 0; kc < 64; ++kc){
    if (kc < 63) stage(cur ^ 1, (kc + 1) * 64);   // prefetch hides under MFMA
    const char* Ac = (const char*)&As[cur][0];
    const char* Bc = (const char*)&Bs[cur][0];
    #pragma unroll
    for (int kk = 0; kk < 2; ++kk){
      bffrag af[4], bfr[4];
      #pragma unroll
      for (int i = 0; i < 4; ++i)
        af[i] = *(const bffrag*)(Ac +
            (((wr + i * 16 + fr) * 128 + kk * 64 + quad * 16) ^ rxor));
      #pragma unroll
      for (int j = 0; j < 4; ++j)
        bfr[j] = *(const bffrag*)(Bc +
            (((wc + j * 16 + fr) * 128 + kk * 64 + quad * 16) ^ rxor));
      #pragma unroll
      for (int i = 0; i < 4; ++i)
        #pragma unroll
        for (int j = 0; j < 4; ++j)
          acc[i][j] = __builtin_amdgcn_mfma_f32_16x16x32_bf16(af[i], bfr[j], acc[i][j], 0, 0, 0);
    }
    __syncthreads();                     // drains prefetch vmcnt + joins waves
    cur ^= 1;
  }

  unsigned short* op = Ab + (size_t)b * C_ * C_;
  #pragma unroll
  for (int i = 0; i < 4; ++i)
    #pragma unroll
    for (int r = 0; r < 4; ++r){
      int c = c0 + wr + i * 16 + quad * 4 + r;
      #pragma unroll
      for (int j = 0; j < 4; ++j)
        op[(size_t)c * C_ + m0 + wc + j * 16 + fr] = f2bf(acc[i][j][r]);
    }
}

// ---------------------------------------------------------------------------
// K3: GEMM2 + epilogue. A = Ab[c][m], B = Pt[n][m], K=512, BK=32,
// double-buffered (32KB LDS) + prefetch-before-compute. 64B LDS rows ->
// swizzle chunk ^= (row>>1)&3 (2-way residual = free). Epilogue stores
// straight from acc fragments (4x64B segments/inst) -- no LDS bounce, so
// LDS = 32.5KB and __launch_bounds__(256,4) gives 4 blocks/CU.
// ---------------------------------------------------------------------------
__global__ __launch_bounds__(256, 4) void k_gemm2(const float* __restrict__ x,
    const unsigned short* __restrict__ Ab, const unsigned short* __restrict__ Pt,
    const float* __restrict__ vsum, const float* __restrict__ sqg,
    const float* __restrict__ tvec, const float* __restrict__ gamma,
    float* __restrict__ out){
  const int b  = blockIdx.y;
  const int c0 = (blockIdx.x >> 5) * 128, n0 = (blockIdx.x & 31) * 128;

  __shared__ unsigned short As[2][4096], Bs[2][4096];   // [buf][128 rows][32 k]
  __shared__ float tl[128];

  const int t = threadIdx.x, lane = t & 63, wave = t >> 6;
  if (t < 128) tl[t] = 1.0f / ((float)N_ + tvec[b * C_ + c0 + t]);
  const int wr = (wave & 1) * 64, wc = (wave >> 1) * 64;
  const int fr = lane & 15, quad = lane >> 4;
  const int rxor = ((fr >> 1) & 3) << 4;  // read swizzle ((row>>1)&3 == (fr>>1)&3)

  // staging: call q covers rows q*64 + (t>>2); chunk = (t&3) ^ ((row>>1)&3)
  const int r2 = t >> 2;
  const int cse = ((t & 3) ^ ((t >> 3) & 3)) * 8;
  const unsigned short* Ag = Ab + (size_t)b * C_ * C_ + (size_t)(c0 + r2) * C_ + cse;
  const unsigned short* Bg = Pt + ((size_t)b * N_ + n0 + r2) * C_ + cse;
  const int lo = wave * 512;             // elements; HW adds lane*8

  f32x4 acc[4][4];
  #pragma unroll
  for (int i = 0; i < 4; ++i)
    #pragma unroll
    for (int j = 0; j < 4; ++j) acc[i][j] = (f32x4){0.f, 0.f, 0.f, 0.f};

  auto stage = [&](int bufi, int k0){
    gload_lds16(Ag + k0,           &As[bufi][lo]);
    gload_lds16(Ag + 64 * C_ + k0, &As[bufi][2048 + lo]);
    gload_lds16(Bg + k0,           &Bs[bufi][lo]);
    gload_lds16(Bg + 64 * C_ + k0, &Bs[bufi][2048 + lo]);
  };

  stage(0, 0);
  __syncthreads();
  int cur = 0;
  for (int kc = 0; kc < 16; ++kc){
    if (kc < 15) stage(cur ^ 1, (kc + 1) * 32);
    const char* Ac = (const char*)&As[cur][0];
    const char* Bc = (const char*)&Bs[cur][0];
    bffrag af[4], bfr[4];
    #pragma unroll
    for (int i = 0; i < 4; ++i)
      af[i] = *(const bffrag*)(Ac + (((wr + i * 16 + fr) * 64 + quad * 16) ^ rxor));
    #pragma unroll
    for (int j = 0; j < 4; ++j)
      bfr[j] = *(const bffrag*)(Bc + (((wc + j * 16 + fr) * 64 + quad * 16) ^ rxor));
    #pragma unroll
    for (int i = 0; i < 4; ++i)
      #pragma unroll
      for (int j = 0; j < 4; ++j)
        acc[i][j] = __builtin_amdgcn_mfma_f32_16x16x32_bf16(af[i], bfr[j], acc[i][j], 0, 0, 0);
    __syncthreads();
    cur ^= 1;
  }

  // epilogue: direct RMW from acc. Per inst: 4 c-rows x 16 consecutive n
  // = 4x64B segments (coalesced enough for HBM).
  const float g = gamma[0];
  float vsn[4], sqn[4];
  #pragma unroll
  for (int j = 0; j < 4; ++j){
    int n = n0 + wc + j * 16 + fr;
    vsn[j] = vsum[b * N_ + n];
    sqn[j] = sqg[b * N_ + n];
  }
  const size_t bofs = (size_t)b * C_ * N_;
  #pragma unroll
  for (int i = 0; i < 4; ++i)
    #pragma unroll
    for (int r = 0; r < 4; ++r){
      int cl = wr + i * 16 + quad * 4 + r;
      float tlc = tl[cl];
      const float* xr = x + bofs + (size_t)(c0 + cl) * N_ + n0;
      float* orow    = out + bofs + (size_t)(c0 + cl) * N_ + n0;
      #pragma unroll
      for (int j = 0; j < 4; ++j){
        int n = wc + j * 16 + fr;
        orow[n] = xr[n] + g * ((vsn[j] + sqn[j] * acc[i][j][r]) * tlc);
      }
    }
}

// ---------------------------------------------------------------------------
extern "C" void kernel_launch(void* const* d_in, const int* in_sizes, int n_in,
                              void* d_out, int out_size, void* d_ws, size_t ws_size,
                              hipStream_t stream){
  const float* x     = (const float*)d_in[0];
  const float* gamma = (const float*)d_in[1];
  float* out = (float*)d_out;
  char* ws = (char*)d_ws;

  // ws layout (bytes):
  unsigned short* Ph = (unsigned short*)(ws);              //  67,108,864
  unsigned short* Pt = (unsigned short*)(ws + 67108864);   //  67,108,864
  unsigned short* Ab = (unsigned short*)(ws + 134217728);  //   8,388,608
  float* tpart = (float*)(ws + 142606336);                 //   2,097,152
  float* vsum  = (float*)(ws + 144703488);                 //     262,144
  float* sqg   = (float*)(ws + 144965632);                 //     262,144
  float* tvec  = (float*)(ws + 145227776);                 //      32,768
  // total 145,260,544 bytes

  k_prep<<<dim3(B_ * 64), 256, 0, stream>>>(x, Ph, Pt, vsum, sqg, tpart);
  k_gemm1<<<dim3(272), 256, 0, stream>>>(Ph, Ab, tpart, tvec);
  k_gemm2<<<dim3(128, B_), 256, 0, stream>>>(x, Ab, Pt, vsum, sqg, tvec, gamma, out);
}

// Round 2
// 451.234 us; speedup vs baseline: 1.1013x; 1.1013x over previous
//
#include <hip/hip_runtime.h>
#include <hip/hip_bf16.h>

#define B_ 16
#define C_ 512
#define N_ 4096
#define EPSV 1e-6f

typedef __attribute__((ext_vector_type(8))) short bffrag;     // 8 bf16 (4 VGPR) MFMA A/B frag
typedef __attribute__((ext_vector_type(4))) float f32x4;      // MFMA C/D frag
typedef __attribute__((ext_vector_type(2))) unsigned short us2;
typedef __attribute__((ext_vector_type(4))) unsigned short us4;
typedef __attribute__((ext_vector_type(8))) unsigned short us8;

__device__ __forceinline__ unsigned short f2bf(float f){
  unsigned u = __float_as_uint(f);
  u += 0x7fffu + ((u >> 16) & 1u);   // RNE; inputs are finite gaussians
  return (unsigned short)(u >> 16);
}

// async global->LDS, 16B/lane; LDS base must be wave-uniform, HW scatters
// lane i to base + i*16. Global source IS per-lane -> swizzled LDS layouts
// are done by pre-swizzling the global source address (m173 pattern).
__device__ __forceinline__ void gload_lds16(const void* g, void* l){
  __builtin_amdgcn_global_load_lds(
      (__attribute__((address_space(1))) void*)g,
      (__attribute__((address_space(3))) void*)l, 16, 0, 0);
}

#define SBAR()  __builtin_amdgcn_s_barrier()
#define SCHED0() __builtin_amdgcn_sched_barrier(0)
#define WAITV(N) asm volatile("s_waitcnt vmcnt(" #N ")" ::: "memory")
#define WAITL0() asm volatile("s_waitcnt lgkmcnt(0)" ::: "memory")

// ---------------------------------------------------------------------------
// K1: fused reduce+prep (unchanged from R1). Block = (b, 64-n strip).
// ---------------------------------------------------------------------------
__global__ __launch_bounds__(256) void k_prep(const float* __restrict__ x,
    unsigned short* __restrict__ Ph, unsigned short* __restrict__ Pt,
    float* __restrict__ vsum, float* __restrict__ sqg,
    float* __restrict__ tpart){
  __shared__ float sdA[16][64], sdB[16][64];
  __shared__ float sql[64], rql[64];
  __shared__ unsigned short qtl[512 * 66];   // [c][nloc], stride 66 breaks banks

  const int t = threadIdx.x;
  const int b = blockIdx.x >> 6, strip = blockIdx.x & 63, n0 = strip * 64;
  const int rg = t >> 4, n4 = t & 15;
  const float* xs = x + (size_t)b * C_ * N_ + n0;

  // pass A: column sums
  float4 s4 = {0,0,0,0}, s24 = {0,0,0,0};
  #pragma unroll 8
  for (int k = 0; k < 32; ++k){
    float4 v = *(const float4*)&xs[(size_t)(k * 16 + rg) * N_ + n4 * 4];
    s4.x += v.x; s4.y += v.y; s4.z += v.z; s4.w += v.w;
    s24.x += v.x * v.x; s24.y += v.y * v.y;
    s24.z += v.z * v.z; s24.w += v.w * v.w;
  }
  *(float4*)&sdA[rg][n4 * 4] = s4;
  *(float4*)&sdB[rg][n4 * 4] = s24;
  __syncthreads();
  if (t < 64){
    float s = 0.f, s2 = 0.f;
    #pragma unroll
    for (int g2 = 0; g2 < 16; ++g2){ s += sdA[g2][t]; s2 += sdB[g2][t]; }
    float rn = 1.0f / sqrtf(s2);
    float sq = sqrtf(rn);
    vsum[b * N_ + n0 + t] = s;
    sqg [b * N_ + n0 + t] = sq;
    sql[t] = sq;
    rql[t] = rn * (s * rn + EPSV);
  }
  __syncthreads();

  // pass B
  float4 sq4 = *(float4*)&sql[n4 * 4];
  float4 rq4 = *(float4*)&rql[n4 * 4];
  unsigned short* Php = Ph + (size_t)b * C_ * N_ + n0;
  float* tpp = tpart + ((size_t)b * 64 + strip) * C_;
  #pragma unroll 4
  for (int k = 0; k < 32; ++k){
    int c = k * 16 + rg;
    float4 v = *(const float4*)&xs[(size_t)c * N_ + n4 * 4];
    us2 p0, p1;
    p0.x = f2bf(v.x * sq4.x); p0.y = f2bf(v.y * sq4.y);
    p1.x = f2bf(v.z * sq4.z); p1.y = f2bf(v.w * sq4.w);
    us4 ph; ph.x = p0.x; ph.y = p0.y; ph.z = p1.x; ph.w = p1.y;
    *(us4*)&Php[(size_t)c * N_ + n4 * 4] = ph;
    *(us2*)&qtl[c * 66 + n4 * 4]     = p0;   // 4B-aligned (66c+4n4 even)
    *(us2*)&qtl[c * 66 + n4 * 4 + 2] = p1;
    float tp = v.x * rq4.x + v.y * rq4.y + v.z * rq4.z + v.w * rq4.w;
    tp += __shfl_down(tp, 8, 16);
    tp += __shfl_down(tp, 4, 16);
    tp += __shfl_down(tp, 2, 16);
    tp += __shfl_down(tp, 1, 16);
    if (n4 == 0) tpp[c] = tp;
  }
  __syncthreads();

  // transposed output Pt[b][n][c]: us2 LDS reads feed us8 (16B) stores.
  {
    const int n2 = (t & 31) * 2, cg = (t >> 5) * 64;
    unsigned short* P0 = Pt + ((size_t)b * N_ + n0 + n2) * C_;
    unsigned short* P1 = P0 + C_;
    for (int k8 = 0; k8 < 8; ++k8){
      int c = cg + k8 * 8;
      us8 w0, w1;
      #pragma unroll
      for (int e = 0; e < 8; ++e){
        us2 v = *(const us2*)&qtl[(c + e) * 66 + n2];
        w0[e] = v.x; w1[e] = v.y;
      }
      *(us8*)&P0[c] = w0;
      *(us8*)&P1[c] = w1;
    }
  }
}

// ---------------------------------------------------------------------------
// K2: GEMM1  matrix = Ph @ Ph^T per batch, K=4096, bf16 out.
// 4 waves x 64x64 acc, BK=64, double-buffered + COUNTED vmcnt(8) pipeline:
// prefetch loads stay in flight across the raw s_barrier (T4); never drain
// to 0 in the main loop. Swizzle: source-side chunk^=(row&7), read-side XOR.
// ---------------------------------------------------------------------------
__global__ __launch_bounds__(256) void k_gemm1(const unsigned short* __restrict__ Ph,
    unsigned short* __restrict__ Ab, const float* __restrict__ tpart,
    float* __restrict__ tvec){
  const int bid = blockIdx.x;
  if (bid >= 256){                       // tail: tvec[b*C+c] = sum_strips tpart
    const int base = (bid - 256) * 512;
    for (int u = threadIdx.x; u < 512; u += 256){
      int i = base + u;
      const float* tp = tpart + (size_t)(i >> 9) * 64 * C_ + (i & 511);
      float s = 0.f;
      #pragma unroll 8
      for (int k = 0; k < 64; ++k) s += tp[(size_t)k * C_];
      tvec[i] = s;
    }
    return;
  }
  // bijective bid -> (b, c0, m0): XCD xcd = bid&7 owns 2x2 tile quads
  const int xcd = bid & 7, sq_ = bid >> 3;
  const int qg = xcd * 8 + (sq_ >> 2), sub = sq_ & 3;
  const int b = qg >> 2, qd = qg & 3;
  const int c0 = ((qd >> 1) * 2 + (sub >> 1)) * 128;
  const int m0 = ((qd & 1) * 2 + (sub & 1)) * 128;

  __shared__ unsigned short As[2][8192], Bs[2][8192];   // [buf][128 rows][64 k]

  const int t = threadIdx.x, lane = t & 63, wave = t >> 6;
  const int wr = (wave & 1) * 64, wc = (wave >> 1) * 64;
  const int fr = lane & 15, quad = lane >> 4;
  const int rxor = (fr & 7) << 4;        // read-side swizzle (row&7 == fr&7)

  // staging: call q covers rows q*32 + (t>>3); source chunk = (t&7) ^ (row&7)
  const int rq = t >> 3;
  const int csel = ((t & 7) ^ (rq & 7)) * 8;
  const unsigned short* Aga = Ph + (size_t)(b * C_ + c0 + rq) * N_ + csel;
  const unsigned short* Bga = Ph + (size_t)(b * C_ + m0 + rq) * N_ + csel;
  const int lo = wave * 512;             // elements; HW adds lane*8

  f32x4 acc[4][4];
  #pragma unroll
  for (int i = 0; i < 4; ++i)
    #pragma unroll
    for (int j = 0; j < 4; ++j) acc[i][j] = (f32x4){0.f, 0.f, 0.f, 0.f};

  auto stage = [&](int bufi, int k0){
    gload_lds16(Aga + k0,           &As[bufi][lo]);
    gload_lds16(Aga + 32 * N_ + k0, &As[bufi][2048 + lo]);
    gload_lds16(Aga + 64 * N_ + k0, &As[bufi][4096 + lo]);
    gload_lds16(Aga + 96 * N_ + k0, &As[bufi][6144 + lo]);
    gload_lds16(Bga + k0,           &Bs[bufi][lo]);
    gload_lds16(Bga + 32 * N_ + k0, &Bs[bufi][2048 + lo]);
    gload_lds16(Bga + 64 * N_ + k0, &Bs[bufi][4096 + lo]);
    gload_lds16(Bga + 96 * N_ + k0, &Bs[bufi][6144 + lo]);
  };

  stage(0, 0);
  int cur = 0;
  for (int kc = 0; kc < 64; ++kc){
    if (kc < 63){
      stage(cur ^ 1, (kc + 1) * 64);     // 8 loads issued, stay in flight
      SCHED0();
      WAITV(8);                          // wait ONLY buf[cur]'s 8 (issued last iter)
    } else {
      WAITV(0);
    }
    SBAR();                              // all waves have buf[cur] landed
    SCHED0();
    const char* Ac = (const char*)&As[cur][0];
    const char* Bc = (const char*)&Bs[cur][0];
    #pragma unroll
    for (int kk = 0; kk < 2; ++kk){
      bffrag af[4], bfr[4];
      #pragma unroll
      for (int i = 0; i < 4; ++i)
        af[i] = *(const bffrag*)(Ac +
            (((wr + i * 16 + fr) * 128 + kk * 64 + quad * 16) ^ rxor));
      #pragma unroll
      for (int j = 0; j < 4; ++j)
        bfr[j] = *(const bffrag*)(Bc +
            (((wc + j * 16 + fr) * 128 + kk * 64 + quad * 16) ^ rxor));
      #pragma unroll
      for (int i = 0; i < 4; ++i)
        #pragma unroll
        for (int j = 0; j < 4; ++j)
          acc[i][j] = __builtin_amdgcn_mfma_f32_16x16x32_bf16(af[i], bfr[j], acc[i][j], 0, 0, 0);
    }
    SCHED0();
    SBAR();                              // all waves done reading buf[cur]
    cur ^= 1;
  }

  unsigned short* op = Ab + (size_t)b * C_ * C_;
  #pragma unroll
  for (int i = 0; i < 4; ++i)
    #pragma unroll
    for (int r = 0; r < 4; ++r){
      int c = c0 + wr + i * 16 + quad * 4 + r;
      #pragma unroll
      for (int j = 0; j < 4; ++j)
        op[(size_t)c * C_ + m0 + wc + j * 16 + fr] = f2bf(acc[i][j][r]);
    }
}

// ---------------------------------------------------------------------------
// K3: GEMM2 + epilogue. A = Ab[c][m], B = Pt[n][m], K=512, BK=32,
// double-buffered + counted vmcnt(4) pipeline (T4). Epilogue: chunked LDS
// bounce -- 4 passes of a 32x132 fp32 tile (16.9KB, unioned into the 32KB
// staging LDS) -> float4 coalesced RMW (512B/wave-inst). LDS stays ~33KB.
// ---------------------------------------------------------------------------
__global__ __launch_bounds__(256) void k_gemm2(const float* __restrict__ x,
    const unsigned short* __restrict__ Ab, const unsigned short* __restrict__ Pt,
    const float* __restrict__ vsum, const float* __restrict__ sqg,
    const float* __restrict__ tvec, const float* __restrict__ gamma,
    float* __restrict__ out){
  const int b  = blockIdx.y;
  const int c0 = (blockIdx.x >> 5) * 128, n0 = (blockIdx.x & 31) * 128;

  __shared__ __align__(16) char smem[32768];
  unsigned short* As0 = (unsigned short*)smem;   // [2][4096] us = 16KB
  unsigned short* Bs0 = As0 + 8192;              // [2][4096] us = 16KB
  float (*eps)[132]   = (float(*)[132])smem;     // epilogue 32x132 fp32 = 16.9KB
  __shared__ float tl[128];

  const int t = threadIdx.x, lane = t & 63, wave = t >> 6;
  if (t < 128) tl[t] = 1.0f / ((float)N_ + tvec[b * C_ + c0 + t]);
  const int wr = (wave & 1) * 64, wc = (wave >> 1) * 64;
  const int fr = lane & 15, quad = lane >> 4;
  const int rxor = ((fr >> 1) & 3) << 4;  // read swizzle ((row>>1)&3 == (fr>>1)&3)

  // staging: call q covers rows q*64 + (t>>2); chunk = (t&3) ^ ((row>>1)&3)
  const int r2 = t >> 2;
  const int cse = ((t & 3) ^ ((t >> 3) & 3)) * 8;
  const unsigned short* Ag = Ab + (size_t)b * C_ * C_ + (size_t)(c0 + r2) * C_ + cse;
  const unsigned short* Bg = Pt + ((size_t)b * N_ + n0 + r2) * C_ + cse;
  const int lo = wave * 512;             // elements; HW adds lane*8

  f32x4 acc[4][4];
  #pragma unroll
  for (int i = 0; i < 4; ++i)
    #pragma unroll
    for (int j = 0; j < 4; ++j) acc[i][j] = (f32x4){0.f, 0.f, 0.f, 0.f};

  auto stage = [&](int bufi, int k0){
    gload_lds16(Ag + k0,           As0 + bufi * 4096 + lo);
    gload_lds16(Ag + 64 * C_ + k0, As0 + bufi * 4096 + 2048 + lo);
    gload_lds16(Bg + k0,           Bs0 + bufi * 4096 + lo);
    gload_lds16(Bg + 64 * C_ + k0, Bs0 + bufi * 4096 + 2048 + lo);
  };

  stage(0, 0);
  int cur = 0;
  for (int kc = 0; kc < 16; ++kc){
    if (kc < 15){
      stage(cur ^ 1, (kc + 1) * 32);     // 4 loads issued, stay in flight
      SCHED0();
      WAITV(4);                          // wait ONLY buf[cur]'s 4
    } else {
      WAITV(0);
    }
    SBAR();
    SCHED0();
    const char* Ac = (const char*)(As0 + cur * 4096);
    const char* Bc = (const char*)(Bs0 + cur * 4096);
    bffrag af[4], bfr[4];
    #pragma unroll
    for (int i = 0; i < 4; ++i)
      af[i] = *(const bffrag*)(Ac + (((wr + i * 16 + fr) * 64 + quad * 16) ^ rxor));
    #pragma unroll
    for (int j = 0; j < 4; ++j)
      bfr[j] = *(const bffrag*)(Bc + (((wc + j * 16 + fr) * 64 + quad * 16) ^ rxor));
    #pragma unroll
    for (int i = 0; i < 4; ++i)
      #pragma unroll
      for (int j = 0; j < 4; ++j)
        acc[i][j] = __builtin_amdgcn_mfma_f32_16x16x32_bf16(af[i], bfr[j], acc[i][j], 0, 0, 0);
    SCHED0();
    SBAR();                              // all waves done reading buf[cur]
    cur ^= 1;
  }

  // ---- epilogue: 4 passes, each bounces 32 c-rows x 128 n-cols via LDS ----
  const float g = gamma[0];
  const int col4 = (t & 31) * 4;                       // n-offset, fixed/thread
  float4 v4 = *(const float4*)&vsum[(size_t)b * N_ + n0 + col4];
  float4 s4 = *(const float4*)&sqg [(size_t)b * N_ + n0 + col4];
  const size_t bofs = (size_t)b * C_ * N_;
  const int rbase = (wave & 1) * 16 + quad * 4;        // LDS row for writes

  #pragma unroll
  for (int i = 0; i < 4; ++i){
    // write acc[i][*][*] -> eps[32][132]  (2-way banks = free)
    #pragma unroll
    for (int r = 0; r < 4; ++r)
      #pragma unroll
      for (int j = 0; j < 4; ++j)
        eps[rbase + r][wc + j * 16 + fr] = acc[i][j][r];
    WAITL0();
    SCHED0();
    SBAR();
    SCHED0();
    // read back as float4 rows, fused RMW (512B contiguous per wave-inst)
    #pragma unroll
    for (int p = 0; p < 4; ++p){
      int row = p * 8 + (t >> 5);                      // 0..31
      int cg  = ((row >> 4) << 6) + i * 16 + (row & 15);   // c offset in tile
      float4 a  = *(const float4*)&eps[row][col4];
      const float* xr = x   + bofs + (size_t)(c0 + cg) * N_ + n0;
      float* orow     = out + bofs + (size_t)(c0 + cg) * N_ + n0;
      float4 xv = *(const float4*)&xr[col4];
      float tlc = tl[cg];
      float4 o;
      o.x = xv.x + g * ((v4.x + s4.x * a.x) * tlc);
      o.y = xv.y + g * ((v4.y + s4.y * a.y) * tlc);
      o.z = xv.z + g * ((v4.z + s4.z * a.z) * tlc);
      o.w = xv.w + g * ((v4.w + s4.w * a.w) * tlc);
      *(float4*)&orow[col4] = o;
    }
    SCHED0();
    SBAR();                              // reads done before next pass writes
    SCHED0();
  }
}

// ---------------------------------------------------------------------------
extern "C" void kernel_launch(void* const* d_in, const int* in_sizes, int n_in,
                              void* d_out, int out_size, void* d_ws, size_t ws_size,
                              hipStream_t stream){
  const float* x     = (const float*)d_in[0];
  const float* gamma = (const float*)d_in[1];
  float* out = (float*)d_out;
  char* ws = (char*)d_ws;

  // ws layout (bytes):
  unsigned short* Ph = (unsigned short*)(ws);              //  67,108,864
  unsigned short* Pt = (unsigned short*)(ws + 67108864);   //  67,108,864
  unsigned short* Ab = (unsigned short*)(ws + 134217728);  //   8,388,608
  float* tpart = (float*)(ws + 142606336);                 //   2,097,152
  float* vsum  = (float*)(ws + 144703488);                 //     262,144
  float* sqg   = (float*)(ws + 144965632);                 //     262,144
  float* tvec  = (float*)(ws + 145227776);                 //      32,768
  // total 145,260,544 bytes

  k_prep<<<dim3(B_ * 64), 256, 0, stream>>>(x, Ph, Pt, vsum, sqg, tpart);
  k_gemm1<<<dim3(272), 256, 0, stream>>>(Ph, Ab, tpart, tvec);
  k_gemm2<<<dim3(128, B_), 256, 0, stream>>>(x, Ab, Pt, vsum, sqg, tvec, gamma, out);
}

// Round 3
// 417.416 us; speedup vs baseline: 1.1905x; 1.0810x over previous
//
#include <hip/hip_runtime.h>
#include <hip/hip_bf16.h>

#define B_ 16
#define C_ 512
#define N_ 4096
#define EPSV 1e-6f

typedef __attribute__((ext_vector_type(8))) short bffrag;     // 8 bf16 (4 VGPR) MFMA A/B frag
typedef __attribute__((ext_vector_type(4))) float f32x4;      // MFMA C/D frag
typedef __attribute__((ext_vector_type(2))) unsigned short us2;
typedef __attribute__((ext_vector_type(4))) unsigned short us4;
typedef __attribute__((ext_vector_type(8))) unsigned short us8;

__device__ __forceinline__ unsigned short f2bf(float f){
  unsigned u = __float_as_uint(f);
  u += 0x7fffu + ((u >> 16) & 1u);   // RNE; inputs are finite gaussians
  return (unsigned short)(u >> 16);
}

// async global->LDS, 16B/lane; LDS base must be wave-uniform, HW scatters
// lane i to base + i*16. Global source IS per-lane -> swizzled LDS layouts
// are done by pre-swizzling the global source address (m173 pattern).
__device__ __forceinline__ void gload_lds16(const void* g, void* l){
  __builtin_amdgcn_global_load_lds(
      (__attribute__((address_space(1))) void*)g,
      (__attribute__((address_space(3))) void*)l, 16, 0, 0);
}

#define SBAR()  __builtin_amdgcn_s_barrier()
#define SCHED0() __builtin_amdgcn_sched_barrier(0)
#define WAITV(N) asm volatile("s_waitcnt vmcnt(" #N ")" ::: "memory")
#define WAITL0() asm volatile("s_waitcnt lgkmcnt(0)" ::: "memory")

// ---------------------------------------------------------------------------
// K1: fused reduce+prep. Block = (b, 64-n strip).
// R3: (a) LDS cut 76.3KB -> 33.8KB (c processed in two 256-halves; pass-A
// arrays aliased into the transpose buffer) -> 4 blocks/CU.
// (b) Pt transpose store remapped: thread (rp=t>>3, o=t&7) owns row-pair
// 2rp and 16B chunk o; each wave-inst writes 8 rows x contiguous 128B
// segments (full lines complete within one inst -> no partial-line
// eviction / write amplification). LDS reads for this mapping: bank =
// (8o + rp + e) mod 32 -> exactly 2 lanes/bank = free.
// ---------------------------------------------------------------------------
__global__ __launch_bounds__(256) void k_prep(const float* __restrict__ x,
    unsigned short* __restrict__ Ph, unsigned short* __restrict__ Pt,
    float* __restrict__ vsum, float* __restrict__ sqg,
    float* __restrict__ tpart){
  __shared__ __align__(16) char smem[256 * 66 * 2];     // 33792 B
  float (*sdA)[64] = (float(*)[64])smem;                // 4KB   (pass A)
  float (*sdB)[64] = (float(*)[64])(smem + 4096);       // 4KB   (pass A)
  float* sql = (float*)(smem + 8192);                   // 256B  (pass A out)
  float* rql = (float*)(smem + 8448);                   // 256B  (pass A out)
  unsigned short* qtl = (unsigned short*)smem;          // pass-B alias [256][66]

  const int t = threadIdx.x;
  const int b = blockIdx.x >> 6, strip = blockIdx.x & 63, n0 = strip * 64;
  const int rg = t >> 4, n4 = t & 15;
  const float* xs = x + (size_t)b * C_ * N_ + n0;

  // pass A: column sums over all 512 c
  float4 s4 = {0,0,0,0}, s24 = {0,0,0,0};
  #pragma unroll 8
  for (int k = 0; k < 32; ++k){
    float4 v = *(const float4*)&xs[(size_t)(k * 16 + rg) * N_ + n4 * 4];
    s4.x += v.x; s4.y += v.y; s4.z += v.z; s4.w += v.w;
    s24.x += v.x * v.x; s24.y += v.y * v.y;
    s24.z += v.z * v.z; s24.w += v.w * v.w;
  }
  *(float4*)&sdA[rg][n4 * 4] = s4;
  *(float4*)&sdB[rg][n4 * 4] = s24;
  __syncthreads();
  if (t < 64){
    float s = 0.f, s2 = 0.f;
    #pragma unroll
    for (int g2 = 0; g2 < 16; ++g2){ s += sdA[g2][t]; s2 += sdB[g2][t]; }
    float rn = 1.0f / sqrtf(s2);
    float sq = sqrtf(rn);
    vsum[b * N_ + n0 + t] = s;
    sqg [b * N_ + n0 + t] = sq;
    sql[t] = sq;
    rql[t] = rn * (s * rn + EPSV);
  }
  __syncthreads();
  float4 sq4 = *(float4*)&sql[n4 * 4];
  float4 rq4 = *(float4*)&rql[n4 * 4];
  __syncthreads();                       // scales in regs; smem now free for qtl

  unsigned short* Php = Ph + (size_t)b * C_ * N_ + n0;
  float* tpp = tpart + ((size_t)b * 64 + strip) * C_;
  const int rp = t >> 3, o = t & 7;      // transpose roles: row-pair, chunk
  unsigned short* P0 = Pt + ((size_t)b * N_ + n0 + rp * 2) * C_;
  unsigned short* P1 = P0 + C_;

  for (int h = 0; h < 2; ++h){
    // pass B over c-local 0..255 (c = h*256 + cl); x re-read is L2-hot
    #pragma unroll 4
    for (int k = 0; k < 16; ++k){
      int cl = k * 16 + rg, c = h * 256 + cl;
      float4 v = *(const float4*)&xs[(size_t)c * N_ + n4 * 4];
      us2 p0, p1;
      p0.x = f2bf(v.x * sq4.x); p0.y = f2bf(v.y * sq4.y);
      p1.x = f2bf(v.z * sq4.z); p1.y = f2bf(v.w * sq4.w);
      us4 ph; ph.x = p0.x; ph.y = p0.y; ph.z = p1.x; ph.w = p1.y;
      *(us4*)&Php[(size_t)c * N_ + n4 * 4] = ph;
      *(us2*)&qtl[cl * 66 + n4 * 4]     = p0;   // 4B-aligned; 2 lanes/bank
      *(us2*)&qtl[cl * 66 + n4 * 4 + 2] = p1;
      float tp = v.x * rq4.x + v.y * rq4.y + v.z * rq4.z + v.w * rq4.w;
      tp += __shfl_down(tp, 8, 16);
      tp += __shfl_down(tp, 4, 16);
      tp += __shfl_down(tp, 2, 16);
      tp += __shfl_down(tp, 1, 16);
      if (n4 == 0) tpp[c] = tp;
    }
    __syncthreads();
    // transpose store: rows 2rp, 2rp+1; chunks clb = o*8 + 64*i.
    // Per wave-inst: 8 rows x 128B contiguous global segments.
    #pragma unroll
    for (int i = 0; i < 4; ++i){
      int clb = o * 8 + 64 * i;
      us8 w0, w1;
      #pragma unroll
      for (int e = 0; e < 8; ++e){
        us2 v = *(const us2*)&qtl[(clb + e) * 66 + rp * 2];
        w0[e] = v.x; w1[e] = v.y;
      }
      *(us8*)&P0[h * 256 + clb] = w0;
      *(us8*)&P1[h * 256 + clb] = w1;
    }
    __syncthreads();                     // qtl reads done before next half
  }
}

// ---------------------------------------------------------------------------
// K2: GEMM1  matrix = Ph @ Ph^T per batch, K=4096, bf16 out.
// 4 waves x 64x64 acc, BK=64, double-buffered + COUNTED vmcnt(8) pipeline:
// prefetch loads stay in flight across the raw s_barrier (T4); never drain
// to 0 in the main loop. Swizzle: source-side chunk^=(row&7), read-side XOR.
// ---------------------------------------------------------------------------
__global__ __launch_bounds__(256) void k_gemm1(const unsigned short* __restrict__ Ph,
    unsigned short* __restrict__ Ab, const float* __restrict__ tpart,
    float* __restrict__ tvec){
  const int bid = blockIdx.x;
  if (bid >= 256){                       // tail: tvec[b*C+c] = sum_strips tpart
    const int base = (bid - 256) * 512;
    for (int u = threadIdx.x; u < 512; u += 256){
      int i = base + u;
      const float* tp = tpart + (size_t)(i >> 9) * 64 * C_ + (i & 511);
      float s = 0.f;
      #pragma unroll 8
      for (int k = 0; k < 64; ++k) s += tp[(size_t)k * C_];
      tvec[i] = s;
    }
    return;
  }
  // bijective bid -> (b, c0, m0): XCD xcd = bid&7 owns 2x2 tile quads
  const int xcd = bid & 7, sq_ = bid >> 3;
  const int qg = xcd * 8 + (sq_ >> 2), sub = sq_ & 3;
  const int b = qg >> 2, qd = qg & 3;
  const int c0 = ((qd >> 1) * 2 + (sub >> 1)) * 128;
  const int m0 = ((qd & 1) * 2 + (sub & 1)) * 128;

  __shared__ unsigned short As[2][8192], Bs[2][8192];   // [buf][128 rows][64 k]

  const int t = threadIdx.x, lane = t & 63, wave = t >> 6;
  const int wr = (wave & 1) * 64, wc = (wave >> 1) * 64;
  const int fr = lane & 15, quad = lane >> 4;
  const int rxor = (fr & 7) << 4;        // read-side swizzle (row&7 == fr&7)

  // staging: call q covers rows q*32 + (t>>3); source chunk = (t&7) ^ (row&7)
  const int rq = t >> 3;
  const int csel = ((t & 7) ^ (rq & 7)) * 8;
  const unsigned short* Aga = Ph + (size_t)(b * C_ + c0 + rq) * N_ + csel;
  const unsigned short* Bga = Ph + (size_t)(b * C_ + m0 + rq) * N_ + csel;
  const int lo = wave * 512;             // elements; HW adds lane*8

  f32x4 acc[4][4];
  #pragma unroll
  for (int i = 0; i < 4; ++i)
    #pragma unroll
    for (int j = 0; j < 4; ++j) acc[i][j] = (f32x4){0.f, 0.f, 0.f, 0.f};

  auto stage = [&](int bufi, int k0){
    gload_lds16(Aga + k0,           &As[bufi][lo]);
    gload_lds16(Aga + 32 * N_ + k0, &As[bufi][2048 + lo]);
    gload_lds16(Aga + 64 * N_ + k0, &As[bufi][4096 + lo]);
    gload_lds16(Aga + 96 * N_ + k0, &As[bufi][6144 + lo]);
    gload_lds16(Bga + k0,           &Bs[bufi][lo]);
    gload_lds16(Bga + 32 * N_ + k0, &Bs[bufi][2048 + lo]);
    gload_lds16(Bga + 64 * N_ + k0, &Bs[bufi][4096 + lo]);
    gload_lds16(Bga + 96 * N_ + k0, &Bs[bufi][6144 + lo]);
  };

  stage(0, 0);
  int cur = 0;
  for (int kc = 0; kc < 64; ++kc){
    if (kc < 63){
      stage(cur ^ 1, (kc + 1) * 64);     // 8 loads issued, stay in flight
      SCHED0();
      WAITV(8);                          // wait ONLY buf[cur]'s 8 (issued last iter)
    } else {
      WAITV(0);
    }
    SBAR();                              // all waves have buf[cur] landed
    SCHED0();
    const char* Ac = (const char*)&As[cur][0];
    const char* Bc = (const char*)&Bs[cur][0];
    #pragma unroll
    for (int kk = 0; kk < 2; ++kk){
      bffrag af[4], bfr[4];
      #pragma unroll
      for (int i = 0; i < 4; ++i)
        af[i] = *(const bffrag*)(Ac +
            (((wr + i * 16 + fr) * 128 + kk * 64 + quad * 16) ^ rxor));
      #pragma unroll
      for (int j = 0; j < 4; ++j)
        bfr[j] = *(const bffrag*)(Bc +
            (((wc + j * 16 + fr) * 128 + kk * 64 + quad * 16) ^ rxor));
      #pragma unroll
      for (int i = 0; i < 4; ++i)
        #pragma unroll
        for (int j = 0; j < 4; ++j)
          acc[i][j] = __builtin_amdgcn_mfma_f32_16x16x32_bf16(af[i], bfr[j], acc[i][j], 0, 0, 0);
    }
    SCHED0();
    SBAR();                              // all waves done reading buf[cur]
    cur ^= 1;
  }

  unsigned short* op = Ab + (size_t)b * C_ * C_;
  #pragma unroll
  for (int i = 0; i < 4; ++i)
    #pragma unroll
    for (int r = 0; r < 4; ++r){
      int c = c0 + wr + i * 16 + quad * 4 + r;
      #pragma unroll
      for (int j = 0; j < 4; ++j)
        op[(size_t)c * C_ + m0 + wc + j * 16 + fr] = f2bf(acc[i][j][r]);
    }
}

// ---------------------------------------------------------------------------
// K3: GEMM2 + epilogue. A = Ab[c][m], B = Pt[n][m], K=512, BK=32,
// double-buffered + counted vmcnt(4) pipeline (T4). Epilogue: chunked LDS
// bounce -- 4 passes of a 32x132 fp32 tile (16.9KB, unioned into the 32KB
// staging LDS) -> float4 coalesced RMW (512B/wave-inst). LDS stays ~33KB.
// ---------------------------------------------------------------------------
__global__ __launch_bounds__(256) void k_gemm2(const float* __restrict__ x,
    const unsigned short* __restrict__ Ab, const unsigned short* __restrict__ Pt,
    const float* __restrict__ vsum, const float* __restrict__ sqg,
    const float* __restrict__ tvec, const float* __restrict__ gamma,
    float* __restrict__ out){
  const int b  = blockIdx.y;
  const int c0 = (blockIdx.x >> 5) * 128, n0 = (blockIdx.x & 31) * 128;

  __shared__ __align__(16) char smem[32768];
  unsigned short* As0 = (unsigned short*)smem;   // [2][4096] us = 16KB
  unsigned short* Bs0 = As0 + 8192;              // [2][4096] us = 16KB
  float (*eps)[132]   = (float(*)[132])smem;     // epilogue 32x132 fp32 = 16.9KB
  __shared__ float tl[128];

  const int t = threadIdx.x, lane = t & 63, wave = t >> 6;
  if (t < 128) tl[t] = 1.0f / ((float)N_ + tvec[b * C_ + c0 + t]);
  const int wr = (wave & 1) * 64, wc = (wave >> 1) * 64;
  const int fr = lane & 15, quad = lane >> 4;
  const int rxor = ((fr >> 1) & 3) << 4;  // read swizzle ((row>>1)&3 == (fr>>1)&3)

  // staging: call q covers rows q*64 + (t>>2); chunk = (t&3) ^ ((row>>1)&3)
  const int r2 = t >> 2;
  const int cse = ((t & 3) ^ ((t >> 3) & 3)) * 8;
  const unsigned short* Ag = Ab + (size_t)b * C_ * C_ + (size_t)(c0 + r2) * C_ + cse;
  const unsigned short* Bg = Pt + ((size_t)b * N_ + n0 + r2) * C_ + cse;
  const int lo = wave * 512;             // elements; HW adds lane*8

  f32x4 acc[4][4];
  #pragma unroll
  for (int i = 0; i < 4; ++i)
    #pragma unroll
    for (int j = 0; j < 4; ++j) acc[i][j] = (f32x4){0.f, 0.f, 0.f, 0.f};

  auto stage = [&](int bufi, int k0){
    gload_lds16(Ag + k0,           As0 + bufi * 4096 + lo);
    gload_lds16(Ag + 64 * C_ + k0, As0 + bufi * 4096 + 2048 + lo);
    gload_lds16(Bg + k0,           Bs0 + bufi * 4096 + lo);
    gload_lds16(Bg + 64 * C_ + k0, Bs0 + bufi * 4096 + 2048 + lo);
  };

  stage(0, 0);
  int cur = 0;
  for (int kc = 0; kc < 16; ++kc){
    if (kc < 15){
      stage(cur ^ 1, (kc + 1) * 32);     // 4 loads issued, stay in flight
      SCHED0();
      WAITV(4);                          // wait ONLY buf[cur]'s 4
    } else {
      WAITV(0);
    }
    SBAR();
    SCHED0();
    const char* Ac = (const char*)(As0 + cur * 4096);
    const char* Bc = (const char*)(Bs0 + cur * 4096);
    bffrag af[4], bfr[4];
    #pragma unroll
    for (int i = 0; i < 4; ++i)
      af[i] = *(const bffrag*)(Ac + (((wr + i * 16 + fr) * 64 + quad * 16) ^ rxor));
    #pragma unroll
    for (int j = 0; j < 4; ++j)
      bfr[j] = *(const bffrag*)(Bc + (((wc + j * 16 + fr) * 64 + quad * 16) ^ rxor));
    #pragma unroll
    for (int i = 0; i < 4; ++i)
      #pragma unroll
      for (int j = 0; j < 4; ++j)
        acc[i][j] = __builtin_amdgcn_mfma_f32_16x16x32_bf16(af[i], bfr[j], acc[i][j], 0, 0, 0);
    SCHED0();
    SBAR();                              // all waves done reading buf[cur]
    cur ^= 1;
  }

  // ---- epilogue: 4 passes, each bounces 32 c-rows x 128 n-cols via LDS ----
  const float g = gamma[0];
  const int col4 = (t & 31) * 4;                       // n-offset, fixed/thread
  float4 v4 = *(const float4*)&vsum[(size_t)b * N_ + n0 + col4];
  float4 s4 = *(const float4*)&sqg [(size_t)b * N_ + n0 + col4];
  const size_t bofs = (size_t)b * C_ * N_;
  const int rbase = (wave & 1) * 16 + quad * 4;        // LDS row for writes

  #pragma unroll
  for (int i = 0; i < 4; ++i){
    // write acc[i][*][*] -> eps[32][132]  (2-way banks = free)
    #pragma unroll
    for (int r = 0; r < 4; ++r)
      #pragma unroll
      for (int j = 0; j < 4; ++j)
        eps[rbase + r][wc + j * 16 + fr] = acc[i][j][r];
    WAITL0();
    SCHED0();
    SBAR();
    SCHED0();
    // read back as float4 rows, fused RMW (512B contiguous per wave-inst)
    #pragma unroll
    for (int p = 0; p < 4; ++p){
      int row = p * 8 + (t >> 5);                      // 0..31
      int cg  = ((row >> 4) << 6) + i * 16 + (row & 15);   // c offset in tile
      float4 a  = *(const float4*)&eps[row][col4];
      const float* xr = x   + bofs + (size_t)(c0 + cg) * N_ + n0;
      float* orow     = out + bofs + (size_t)(c0 + cg) * N_ + n0;
      float4 xv = *(const float4*)&xr[col4];
      float tlc = tl[cg];
      float4 o;
      o.x = xv.x + g * ((v4.x + s4.x * a.x) * tlc);
      o.y = xv.y + g * ((v4.y + s4.y * a.y) * tlc);
      o.z = xv.z + g * ((v4.z + s4.z * a.z) * tlc);
      o.w = xv.w + g * ((v4.w + s4.w * a.w) * tlc);
      *(float4*)&orow[col4] = o;
    }
    SCHED0();
    SBAR();                              // reads done before next pass writes
    SCHED0();
  }
}

// ---------------------------------------------------------------------------
extern "C" void kernel_launch(void* const* d_in, const int* in_sizes, int n_in,
                              void* d_out, int out_size, void* d_ws, size_t ws_size,
                              hipStream_t stream){
  const float* x     = (const float*)d_in[0];
  const float* gamma = (const float*)d_in[1];
  float* out = (float*)d_out;
  char* ws = (char*)d_ws;

  // ws layout (bytes):
  unsigned short* Ph = (unsigned short*)(ws);              //  67,108,864
  unsigned short* Pt = (unsigned short*)(ws + 67108864);   //  67,108,864
  unsigned short* Ab = (unsigned short*)(ws + 134217728);  //   8,388,608
  float* tpart = (float*)(ws + 142606336);                 //   2,097,152
  float* vsum  = (float*)(ws + 144703488);                 //     262,144
  float* sqg   = (float*)(ws + 144965632);                 //     262,144
  float* tvec  = (float*)(ws + 145227776);                 //      32,768
  // total 145,260,544 bytes

  k_prep<<<dim3(B_ * 64), 256, 0, stream>>>(x, Ph, Pt, vsum, sqg, tpart);
  k_gemm1<<<dim3(272), 256, 0, stream>>>(Ph, Ab, tpart, tvec);
  k_gemm2<<<dim3(128, B_), 256, 0, stream>>>(x, Ab, Pt, vsum, sqg, tvec, gamma, out);
}

// Round 5
// 409.399 us; speedup vs baseline: 1.2138x; 1.0196x over previous
//
#include <hip/hip_runtime.h>
#include <hip/hip_bf16.h>

#define B_ 16
#define C_ 512
#define N_ 4096
#define EPSV 1e-6f

typedef __attribute__((ext_vector_type(8))) short bffrag;     // 8 bf16 (4 VGPR) MFMA A/B frag
typedef __attribute__((ext_vector_type(4))) float f32x4;      // MFMA C/D frag
typedef __attribute__((ext_vector_type(2))) unsigned short us2;
typedef __attribute__((ext_vector_type(4))) unsigned short us4;
typedef __attribute__((ext_vector_type(8))) unsigned short us8;

__device__ __forceinline__ unsigned short f2bf(float f){
  unsigned u = __float_as_uint(f);
  u += 0x7fffu + ((u >> 16) & 1u);   // RNE; inputs are finite gaussians
  return (unsigned short)(u >> 16);
}

// async global->LDS, 16B/lane; LDS base must be wave-uniform, HW scatters
// lane i to base + i*16. Global source IS per-lane -> swizzled LDS layouts
// are done by pre-swizzling the global source address (m173 pattern).
__device__ __forceinline__ void gload_lds16(const void* g, void* l){
  __builtin_amdgcn_global_load_lds(
      (__attribute__((address_space(1))) void*)g,
      (__attribute__((address_space(3))) void*)l, 16, 0, 0);
}

#define SBAR()  __builtin_amdgcn_s_barrier()
#define SCHED0() __builtin_amdgcn_sched_barrier(0)
#define WAITV(N) asm volatile("s_waitcnt vmcnt(" #N ")" ::: "memory")
#define WAITL0() asm volatile("s_waitcnt lgkmcnt(0)" ::: "memory")
#define PRIO(N) __builtin_amdgcn_s_setprio(N)

// ---------------------------------------------------------------------------
// K1: fused reduce+prep. Block = (b, 64-n strip).
// c processed in FOUR 128-chunks -> LDS 16.9KB -> 8 blocks/CU (100% wave
// occupancy). Pass-A arrays alias the transpose buffer. Pt transpose store:
// thread (rp=t>>3,o=t&7) owns row-pair 2rp, chunk o; per wave-inst 8 rows x
// contiguous 128B segments (no partial-line eviction). LDS reads:
// bank = (8o+rp+e) mod 32 -> 2 lanes/bank = free.
// ---------------------------------------------------------------------------
__global__ __launch_bounds__(256) void k_prep(const float* __restrict__ x,
    unsigned short* __restrict__ Ph, unsigned short* __restrict__ Pt,
    float* __restrict__ vsum, float* __restrict__ sqg,
    float* __restrict__ tpart){
  __shared__ __align__(16) char smem[128 * 66 * 2];     // 16896 B
  float (*sdA)[64] = (float(*)[64])smem;                // 4KB   (pass A)
  float (*sdB)[64] = (float(*)[64])(smem + 4096);       // 4KB   (pass A)
  float* sql = (float*)(smem + 8192);                   // 256B  (pass A out)
  float* rql = (float*)(smem + 8448);                   // 256B  (pass A out)
  unsigned short* qtl = (unsigned short*)smem;          // pass-B alias [128][66]

  const int t = threadIdx.x;
  const int b = blockIdx.x >> 6, strip = blockIdx.x & 63, n0 = strip * 64;
  const int rg = t >> 4, n4 = t & 15;
  const float* xs = x + (size_t)b * C_ * N_ + n0;

  // pass A: column sums over all 512 c
  float4 s4 = {0,0,0,0}, s24 = {0,0,0,0};
  #pragma unroll 8
  for (int k = 0; k < 32; ++k){
    float4 v = *(const float4*)&xs[(size_t)(k * 16 + rg) * N_ + n4 * 4];
    s4.x += v.x; s4.y += v.y; s4.z += v.z; s4.w += v.w;
    s24.x += v.x * v.x; s24.y += v.y * v.y;
    s24.z += v.z * v.z; s24.w += v.w * v.w;
  }
  *(float4*)&sdA[rg][n4 * 4] = s4;
  *(float4*)&sdB[rg][n4 * 4] = s24;
  __syncthreads();
  if (t < 64){
    float s = 0.f, s2 = 0.f;
    #pragma unroll
    for (int g2 = 0; g2 < 16; ++g2){ s += sdA[g2][t]; s2 += sdB[g2][t]; }
    float rn = 1.0f / sqrtf(s2);
    float sq = sqrtf(rn);
    vsum[b * N_ + n0 + t] = s;
    sqg [b * N_ + n0 + t] = sq;
    sql[t] = sq;
    rql[t] = rn * (s * rn + EPSV);
  }
  __syncthreads();
  float4 sq4 = *(float4*)&sql[n4 * 4];
  float4 rq4 = *(float4*)&rql[n4 * 4];
  __syncthreads();                       // scales in regs; smem now free for qtl

  unsigned short* Php = Ph + (size_t)b * C_ * N_ + n0;
  float* tpp = tpart + ((size_t)b * 64 + strip) * C_;
  const int rp = t >> 3, o = t & 7;      // transpose roles: row-pair, chunk
  unsigned short* P0 = Pt + ((size_t)b * N_ + n0 + rp * 2) * C_;
  unsigned short* P1 = P0 + C_;

  for (int h = 0; h < 4; ++h){
    // pass B over c-local 0..127 (c = h*128 + cl); x re-read is L2-hot
    #pragma unroll 4
    for (int k = 0; k < 8; ++k){
      int cl = k * 16 + rg, c = h * 128 + cl;
      float4 v = *(const float4*)&xs[(size_t)c * N_ + n4 * 4];
      us2 p0, p1;
      p0.x = f2bf(v.x * sq4.x); p0.y = f2bf(v.y * sq4.y);
      p1.x = f2bf(v.z * sq4.z); p1.y = f2bf(v.w * sq4.w);
      us4 ph; ph.x = p0.x; ph.y = p0.y; ph.z = p1.x; ph.w = p1.y;
      *(us4*)&Php[(size_t)c * N_ + n4 * 4] = ph;
      *(us2*)&qtl[cl * 66 + n4 * 4]     = p0;   // 4B-aligned; 2 lanes/bank
      *(us2*)&qtl[cl * 66 + n4 * 4 + 2] = p1;
      float tp = v.x * rq4.x + v.y * rq4.y + v.z * rq4.z + v.w * rq4.w;
      tp += __shfl_down(tp, 8, 16);
      tp += __shfl_down(tp, 4, 16);
      tp += __shfl_down(tp, 2, 16);
      tp += __shfl_down(tp, 1, 16);
      if (n4 == 0) tpp[c] = tp;
    }
    __syncthreads();
    // transpose store: rows 2rp, 2rp+1; chunks clb = o*8 + 64*i.
    // Per wave-inst: 8 rows x 128B contiguous global segments.
    #pragma unroll
    for (int i = 0; i < 2; ++i){
      int clb = o * 8 + 64 * i;
      us8 w0, w1;
      #pragma unroll
      for (int e = 0; e < 8; ++e){
        us2 v = *(const us2*)&qtl[(clb + e) * 66 + rp * 2];
        w0[e] = v.x; w1[e] = v.y;
      }
      *(us8*)&P0[h * 128 + clb] = w0;
      *(us8*)&P1[h * 128 + clb] = w1;
    }
    __syncthreads();                     // qtl reads done before next chunk
  }
}

// ---------------------------------------------------------------------------
// K2: GEMM1  matrix = Ph @ Ph^T per batch, K=4096, bf16 out.
// 4 waves x 64x64 acc, BK=64. 3-buffer LDS (96KB, CU has it idle at
// 1 block/CU) + 2-DEEP prefetch: WAITV(16) keeps two 8-load stages in
// flight across barriers -> covers ~2x tile latency. setprio around MFMA.
// ---------------------------------------------------------------------------
__global__ __launch_bounds__(256) void k_gemm1(const unsigned short* __restrict__ Ph,
    unsigned short* __restrict__ Ab, const float* __restrict__ tpart,
    float* __restrict__ tvec){
  const int bid = blockIdx.x;
  if (bid >= 256){                       // tail: tvec[b*C+c] = sum_strips tpart
    const int base = (bid - 256) * 512;
    for (int u = threadIdx.x; u < 512; u += 256){
      int i = base + u;
      const float* tp = tpart + (size_t)(i >> 9) * 64 * C_ + (i & 511);
      float s = 0.f;
      #pragma unroll 8
      for (int k = 0; k < 64; ++k) s += tp[(size_t)k * C_];
      tvec[i] = s;
    }
    return;
  }
  // bijective bid -> (b, c0, m0): XCD xcd = bid&7 owns 2x2 tile quads
  const int xcd = bid & 7, sq_ = bid >> 3;
  const int qg = xcd * 8 + (sq_ >> 2), sub = sq_ & 3;
  const int b = qg >> 2, qd = qg & 3;
  const int c0 = ((qd >> 1) * 2 + (sub >> 1)) * 128;
  const int m0 = ((qd & 1) * 2 + (sub & 1)) * 128;

  __shared__ unsigned short As[3][8192], Bs[3][8192];   // [buf][128 rows][64 k]

  const int t = threadIdx.x, lane = t & 63, wave = t >> 6;
  const int wr = (wave & 1) * 64, wc = (wave >> 1) * 64;
  const int fr = lane & 15, quad = lane >> 4;
  const int rxor = (fr & 7) << 4;        // read-side swizzle (row&7 == fr&7)

  // staging: call q covers rows q*32 + (t>>3); source chunk = (t&7) ^ (row&7)
  const int rq = t >> 3;
  const int csel = ((t & 7) ^ (rq & 7)) * 8;
  const unsigned short* Aga = Ph + (size_t)(b * C_ + c0 + rq) * N_ + csel;
  const unsigned short* Bga = Ph + (size_t)(b * C_ + m0 + rq) * N_ + csel;
  const int lo = wave * 512;             // elements; HW adds lane*8

  f32x4 acc[4][4];
  #pragma unroll
  for (int i = 0; i < 4; ++i)
    #pragma unroll
    for (int j = 0; j < 4; ++j) acc[i][j] = (f32x4){0.f, 0.f, 0.f, 0.f};

  auto stage = [&](int bufi, int k0){
    gload_lds16(Aga + k0,           &As[bufi][lo]);
    gload_lds16(Aga + 32 * N_ + k0, &As[bufi][2048 + lo]);
    gload_lds16(Aga + 64 * N_ + k0, &As[bufi][4096 + lo]);
    gload_lds16(Aga + 96 * N_ + k0, &As[bufi][6144 + lo]);
    gload_lds16(Bga + k0,           &Bs[bufi][lo]);
    gload_lds16(Bga + 32 * N_ + k0, &Bs[bufi][2048 + lo]);
    gload_lds16(Bga + 64 * N_ + k0, &Bs[bufi][4096 + lo]);
    gload_lds16(Bga + 96 * N_ + k0, &Bs[bufi][6144 + lo]);
  };

  stage(0, 0);
  stage(1, 64);
  int cur = 0, nxt = 2;
  for (int kc = 0; kc < 64; ++kc){
    if (kc < 62){
      stage(nxt, (kc + 2) * 64);         // 8 loads; 2 stages stay in flight
      nxt = (nxt == 2) ? 0 : nxt + 1;
      SCHED0();
      WAITV(16);                         // oldest 8 (tile kc) landed
    } else if (kc == 62){
      WAITV(8);
    } else {
      WAITV(0);
    }
    SBAR();                              // all waves have buf[cur] landed
    SCHED0();
    const char* Ac = (const char*)&As[cur][0];
    const char* Bc = (const char*)&Bs[cur][0];
    PRIO(1);
    #pragma unroll
    for (int kk = 0; kk < 2; ++kk){
      bffrag af[4], bfr[4];
      #pragma unroll
      for (int i = 0; i < 4; ++i)
        af[i] = *(const bffrag*)(Ac +
            (((wr + i * 16 + fr) * 128 + kk * 64 + quad * 16) ^ rxor));
      #pragma unroll
      for (int j = 0; j < 4; ++j)
        bfr[j] = *(const bffrag*)(Bc +
            (((wc + j * 16 + fr) * 128 + kk * 64 + quad * 16) ^ rxor));
      #pragma unroll
      for (int i = 0; i < 4; ++i)
        #pragma unroll
        for (int j = 0; j < 4; ++j)
          acc[i][j] = __builtin_amdgcn_mfma_f32_16x16x32_bf16(af[i], bfr[j], acc[i][j], 0, 0, 0);
    }
    PRIO(0);
    SCHED0();
    SBAR();                              // all waves done reading buf[cur]
    cur = (cur == 2) ? 0 : cur + 1;
  }

  unsigned short* op = Ab + (size_t)b * C_ * C_;
  #pragma unroll
  for (int i = 0; i < 4; ++i)
    #pragma unroll
    for (int r = 0; r < 4; ++r){
      int c = c0 + wr + i * 16 + quad * 4 + r;
      #pragma unroll
      for (int j = 0; j < 4; ++j)
        op[(size_t)c * C_ + m0 + wc + j * 16 + fr] = f2bf(acc[i][j][r]);
    }
}

// ---------------------------------------------------------------------------
// K3: GEMM2 + epilogue. A = Ab[c][m], B = Pt[n][m], K=512, BK=32.
// 3-buffer LDS (48KB, 3 blocks/CU) + 2-DEEP prefetch WAITV(8); the
// epilogue vsum/sqg loads are hoisted BEFORE the prologue stages so they
// retire under the first WAITV (vmcnt accounting stays exact). setprio
// around MFMA. Epilogue: 4-pass LDS bounce -> float4 coalesced RMW.
// ---------------------------------------------------------------------------
__global__ __launch_bounds__(256) void k_gemm2(const float* __restrict__ x,
    const unsigned short* __restrict__ Ab, const unsigned short* __restrict__ Pt,
    const float* __restrict__ vsum, const float* __restrict__ sqg,
    const float* __restrict__ tvec, const float* __restrict__ gamma,
    float* __restrict__ out){
  const int b  = blockIdx.y;
  const int c0 = (blockIdx.x >> 5) * 128, n0 = (blockIdx.x & 31) * 128;

  __shared__ __align__(16) char smem[49152];
  unsigned short* As0 = (unsigned short*)smem;   // [3][4096] us = 24KB
  unsigned short* Bs0 = As0 + 12288;             // [3][4096] us = 24KB
  float (*eps)[132]   = (float(*)[132])smem;     // epilogue 32x132 fp32 = 16.9KB
  __shared__ float tl[128];

  const int t = threadIdx.x, lane = t & 63, wave = t >> 6;
  // tvec load + tl write FIRST: compiler's vmcnt wait for the ds_write
  // lands before any stage loads are issued.
  if (t < 128) tl[t] = 1.0f / ((float)N_ + tvec[b * C_ + c0 + t]);
  const int wr = (wave & 1) * 64, wc = (wave >> 1) * 64;
  const int fr = lane & 15, quad = lane >> 4;
  const int rxor = ((fr >> 1) & 3) << 4;  // read swizzle ((row>>1)&3 == (fr>>1)&3)

  // epilogue scale vectors, hoisted ahead of the prologue stages: they are
  // the OLDEST vmem ops, so the first WAITV(8) retires them with tile 0.
  const int col4 = (t & 31) * 4;
  float4 v4 = *(const float4*)&vsum[(size_t)b * N_ + n0 + col4];
  float4 s4 = *(const float4*)&sqg [(size_t)b * N_ + n0 + col4];

  // staging: call q covers rows q*64 + (t>>2); chunk = (t&3) ^ ((row>>1)&3)
  const int r2 = t >> 2;
  const int cse = ((t & 3) ^ ((t >> 3) & 3)) * 8;
  const unsigned short* Ag = Ab + (size_t)b * C_ * C_ + (size_t)(c0 + r2) * C_ + cse;
  const unsigned short* Bg = Pt + ((size_t)b * N_ + n0 + r2) * C_ + cse;
  const int lo = wave * 512;             // elements; HW adds lane*8

  f32x4 acc[4][4];
  #pragma unroll
  for (int i = 0; i < 4; ++i)
    #pragma unroll
    for (int j = 0; j < 4; ++j) acc[i][j] = (f32x4){0.f, 0.f, 0.f, 0.f};

  auto stage = [&](int bufi, int k0){
    gload_lds16(Ag + k0,           As0 + bufi * 4096 + lo);
    gload_lds16(Ag + 64 * C_ + k0, As0 + bufi * 4096 + 2048 + lo);
    gload_lds16(Bg + k0,           Bs0 + bufi * 4096 + lo);
    gload_lds16(Bg + 64 * C_ + k0, Bs0 + bufi * 4096 + 2048 + lo);
  };

  stage(0, 0);
  stage(1, 32);
  int cur = 0, nxt = 2;
  for (int kc = 0; kc < 16; ++kc){
    if (kc < 14){
      stage(nxt, (kc + 2) * 32);         // 4 loads; 2 stages stay in flight
      nxt = (nxt == 2) ? 0 : nxt + 1;
      SCHED0();
      WAITV(8);                          // oldest 4 (tile kc) landed
    } else if (kc == 14){
      WAITV(4);
    } else {
      WAITV(0);
    }
    SBAR();
    SCHED0();
    const char* Ac = (const char*)(As0 + cur * 4096);
    const char* Bc = (const char*)(Bs0 + cur * 4096);
    bffrag af[4], bfr[4];
    #pragma unroll
    for (int i = 0; i < 4; ++i)
      af[i] = *(const bffrag*)(Ac + (((wr + i * 16 + fr) * 64 + quad * 16) ^ rxor));
    #pragma unroll
    for (int j = 0; j < 4; ++j)
      bfr[j] = *(const bffrag*)(Bc + (((wc + j * 16 + fr) * 64 + quad * 16) ^ rxor));
    PRIO(1);
    #pragma unroll
    for (int i = 0; i < 4; ++i)
      #pragma unroll
      for (int j = 0; j < 4; ++j)
        acc[i][j] = __builtin_amdgcn_mfma_f32_16x16x32_bf16(af[i], bfr[j], acc[i][j], 0, 0, 0);
    PRIO(0);
    SCHED0();
    SBAR();                              // all waves done reading buf[cur]
    cur = (cur == 2) ? 0 : cur + 1;
  }

  // ---- epilogue: 4 passes, each bounces 32 c-rows x 128 n-cols via LDS ----
  const float g = gamma[0];
  const size_t bofs = (size_t)b * C_ * N_;
  const int rbase = (wave & 1) * 16 + quad * 4;        // LDS row for writes

  #pragma unroll
  for (int i = 0; i < 4; ++i){
    // write acc[i][*][*] -> eps[32][132]  (2-way banks = free)
    #pragma unroll
    for (int r = 0; r < 4; ++r)
      #pragma unroll
      for (int j = 0; j < 4; ++j)
        eps[rbase + r][wc + j * 16 + fr] = acc[i][j][r];
    WAITL0();
    SCHED0();
    SBAR();
    SCHED0();
    // read back as float4 rows, fused RMW (512B contiguous per wave-inst)
    #pragma unroll
    for (int p = 0; p < 4; ++p){
      int row = p * 8 + (t >> 5);                      // 0..31
      int cg  = ((row >> 4) << 6) + i * 16 + (row & 15);   // c offset in tile
      float4 a  = *(const float4*)&eps[row][col4];
      const float* xr = x   + bofs + (size_t)(c0 + cg) * N_ + n0;
      float* orow     = out + bofs + (size_t)(c0 + cg) * N_ + n0;
      float4 xv = *(const float4*)&xr[col4];
      float tlc = tl[cg];
      float4 o;
      o.x = xv.x + g * ((v4.x + s4.x * a.x) * tlc);
      o.y = xv.y + g * ((v4.y + s4.y * a.y) * tlc);
      o.z = xv.z + g * ((v4.z + s4.z * a.z) * tlc);
      o.w = xv.w + g * ((v4.w + s4.w * a.w) * tlc);
      *(float4*)&orow[col4] = o;
    }
    SCHED0();
    SBAR();                              // reads done before next pass writes
    SCHED0();
  }
}

// ---------------------------------------------------------------------------
extern "C" void kernel_launch(void* const* d_in, const int* in_sizes, int n_in,
                              void* d_out, int out_size, void* d_ws, size_t ws_size,
                              hipStream_t stream){
  const float* x     = (const float*)d_in[0];
  const float* gamma = (const float*)d_in[1];
  float* out = (float*)d_out;
  char* ws = (char*)d_ws;

  // ws layout (bytes):
  unsigned short* Ph = (unsigned short*)(ws);              //  67,108,864
  unsigned short* Pt = (unsigned short*)(ws + 67108864);   //  67,108,864
  unsigned short* Ab = (unsigned short*)(ws + 134217728);  //   8,388,608
  float* tpart = (float*)(ws + 142606336);                 //   2,097,152
  float* vsum  = (float*)(ws + 144703488);                 //     262,144
  float* sqg   = (float*)(ws + 144965632);                 //     262,144
  float* tvec  = (float*)(ws + 145227776);                 //      32,768
  // total 145,260,544 bytes

  k_prep<<<dim3(B_ * 64), 256, 0, stream>>>(x, Ph, Pt, vsum, sqg, tpart);
  k_gemm1<<<dim3(272), 256, 0, stream>>>(Ph, Ab, tpart, tvec);
  k_gemm2<<<dim3(128, B_), 256, 0, stream>>>(x, Ab, Pt, vsum, sqg, tvec, gamma, out);
}